// Round 4
// baseline (299.130 us; speedup 1.0000x reference)
//
#include <hip/hip_runtime.h>
#include <math.h>

// Shift_11261404250938: per-image shift(trunc(±10%)) + zero-fill, standardize,
// min-max normalize. Standardization cancels in the min-max step, so
// out = (shifted - min) / (max - min).
//
// R5 -> R6: split kernels (R3/R5) never beat the fused R0 (sum ~107-116us vs
// 117us): occupancy and VALU hoisting are both proven non-limiters; the split
// just trades launch+tail overhead for occupancy. Also the split kernels fall
// below the rocprof top-5 cutoff -> blind. R6 returns to ONE fused dispatch
// (256 blocks x 1024 thr, visible counters) and consolidates validated wins:
//  - R5 row-wise waves: lane=column-quad, wave walks rows stride 16; all
//    column math (masks, gather bases/clamps) loop-invariant; row math
//    wave-uniform (readfirstlane -> SGPR).
//  - NEW zero-init trick: any shift != 0 => zero-fill exists => seed
//    vmin=vmax=0; phase 1 then SKIPS invalid source rows entirely (no load,
//    no row mask). No-shift case: masks all-1, seed ±inf -> exact.
//  - NEW invalid-dest-row fast path in phase 2: store splat((0-mn)*inv),
//    no loads.
//  - phase 1 unroll 6 (42=6x7) for deep outstanding-load MLP.

constexpr int kC = 3, kH = 224, kW = 224;
constexpr int kCHW  = kC * kH * kW;  // 150528
constexpr int kROWS = kC * kH;       // 672
constexpr int kQPR  = kW / 4;        // 56 quads per row
constexpr int TB    = 1024;          // 16 waves
constexpr int WVB   = TB / 64;       // 16
constexpr int RPW   = kROWS / WVB;   // 42 rows per wave (exact)

typedef float f32x4 __attribute__((ext_vector_type(4)));

// Misaligned-by-sx gather: two aligned float4 loads + compile-time rotate
// (R = sx & 3; base is a multiple of 4, so clamped lanes' wrong elements are
// always fully masked -- property verified R2/R5).
template <int R>
__device__ __forceinline__ void phase2_rows(const float* __restrict__ xb,
                                            float* __restrict__ ob,
                                            int sy, int sx, float inv,
                                            float zoff, int wv, int lane)
{
    if (lane >= kQPR) return;
    const int i0   = lane * 4;
    const int base = i0 + sx - R;                  // multiple of 4
    int qa = base;     qa = qa < 0 ? 0 : qa; qa = qa > kW - 4 ? kW - 4 : qa;
    int qb = base + 4; qb = qb < 0 ? 0 : qb; qb = qb > kW - 4 ? kW - 4 : qb;

    float cm[4];
    #pragma unroll
    for (int k = 0; k < 4; ++k)
        cm[k] = ((unsigned)(i0 + k + sx) < (unsigned)kW) ? 1.0f : 0.0f;
    const f32x4 zq = {zoff, zoff, zoff, zoff};

    #pragma unroll 3
    for (int t = 0; t < RPW; ++t) {
        const int rr = wv + t * WVB;               // output row in [0, C*H)
        const int j  = rr % kH;                    // wave-uniform scalar
        const int jj = j + sy;
        float* __restrict__ dst = ob + rr * kW + i0;
        if ((unsigned)jj < (unsigned)kH) {         // wave-uniform branch
            const float* __restrict__ src = xb + (rr - j + jj) * kW;
            const f32x4 av = *(const f32x4*)(src + qa);
            const f32x4 bv = *(const f32x4*)(src + qb);
            f32x4 o;
            #pragma unroll
            for (int k = 0; k < 4; ++k) {
                const float sel = (k + R < 4) ? av[k + R] : bv[k + R - 4];
                o[k] = fmaf(sel * cm[k], inv, zoff); // invalid -> (0-mn)*inv
            }
            *(f32x4*)dst = o;                      // 16B aligned
        } else {
            *(f32x4*)dst = zq;                     // zero-filled row
        }
    }
}

__global__ __launch_bounds__(TB) void shift_norm(
    const float* __restrict__ x, const float* __restrict__ sfy,
    const float* __restrict__ sfx, float* __restrict__ out)
{
    const int img = blockIdx.x;
    const float* __restrict__ xb = x + (size_t)img * kCHW;
    float* __restrict__ ob = out + (size_t)img * kCHW;

    // Replicate reference fp32 order: ((f*2-1)*0.1f)*size, trunc toward zero.
    float ty = sfy[img] * 2.0f - 1.0f; ty *= 0.1f; ty *= (float)kH;
    const int sy = (int)truncf(ty);
    float tx = sfx[img] * 2.0f - 1.0f; tx *= 0.1f; tx *= (float)kW;
    const int sx = (int)truncf(tx);

    // Valid input sub-rectangle (rows/cols of x that survive the shift).
    const int rlo = sy > 0 ? sy : 0;
    const int rhi = kH + (sy < 0 ? sy : 0);
    const int clo = sx > 0 ? sx : 0;
    const int chi = kW + (sx < 0 ? sx : 0);

    const int tid  = threadIdx.x;
    const int lane = tid & 63;
    const int wv   = __builtin_amdgcn_readfirstlane(tid >> 6); // wave-uniform

    // Any nonzero shift introduces zero-fill -> 0 is in the value set.
    const bool hasfill = (sy != 0) | (sx != 0);
    float vmin = hasfill ? 0.0f : INFINITY;
    float vmax = hasfill ? 0.0f : -INFINITY;

    // ---------------- Phase 1: row-wise streaming min/max ----------------
    if (lane < kQPR) {
        const int i0 = lane * 4;
        float cm[4];                      // loop-invariant column validity
        #pragma unroll
        for (int k = 0; k < 4; ++k)
            cm[k] = ((i0 + k) >= clo && (i0 + k) < chi) ? 1.0f : 0.0f;

        #pragma unroll 6
        for (int t = 0; t < RPW; ++t) {
            const int rr = wv + t * WVB;          // row in [0, C*H)
            const int j  = rr % kH;               // wave-uniform scalar
            if (j >= rlo && j < rhi) {            // skip invalid source rows
                const f32x4 v = *(const f32x4*)(xb + rr * kW + i0);
                #pragma unroll
                for (int k = 0; k < 4; ++k) {
                    const float val = v[k] * cm[k];  // invalid col -> 0 (legal)
                    vmin = fminf(vmin, val);
                    vmax = fmaxf(vmax, val);
                }
            }
        }
    }

    // Wave (64-lane) shuffle reduction, then cross-wave via LDS.
    #pragma unroll
    for (int off = 32; off > 0; off >>= 1) {
        vmin = fminf(vmin, __shfl_down(vmin, off));
        vmax = fmaxf(vmax, __shfl_down(vmax, off));
    }
    __shared__ float smin[WVB], smax[WVB];
    __shared__ float s_mn, s_inv;
    if (lane == 0) { smin[tid >> 6] = vmin; smax[tid >> 6] = vmax; }
    __syncthreads();
    if (tid == 0) {
        float mn = smin[0], mx = smax[0];
        #pragma unroll
        for (int w = 1; w < WVB; ++w) {
            mn = fminf(mn, smin[w]);
            mx = fmaxf(mx, smax[w]);
        }
        s_mn  = mn;
        s_inv = 1.0f / (mx - mn);
    }
    __syncthreads();
    const float mn   = s_mn;
    const float inv  = s_inv;
    const float zoff = (0.0f - mn) * inv;

    // ---------------- Phase 2: gather + normalize + store ----------------
    switch (sx & 3) {
        case 0: phase2_rows<0>(xb, ob, sy, sx, inv, zoff, wv, lane); break;
        case 1: phase2_rows<1>(xb, ob, sy, sx, inv, zoff, wv, lane); break;
        case 2: phase2_rows<2>(xb, ob, sy, sx, inv, zoff, wv, lane); break;
        default: phase2_rows<3>(xb, ob, sy, sx, inv, zoff, wv, lane); break;
    }
}

extern "C" void kernel_launch(void* const* d_in, const int* in_sizes, int n_in,
                              void* d_out, int out_size, void* d_ws, size_t ws_size,
                              hipStream_t stream) {
    const float* x  = (const float*)d_in[0];
    const float* fy = (const float*)d_in[1];
    const float* fx = (const float*)d_in[2];
    float* out = (float*)d_out;
    const int B = in_sizes[1];  // shift_fy has one element per image
    shift_norm<<<B, TB, 0, stream>>>(x, fy, fx, out);
}